// Round 10
// baseline (155.874 us; speedup 1.0000x reference)
//
#include <hip/hip_runtime.h>
#include <math.h>

// MHSA forward. x[16,1024,512]f32, w_qkv[512,1536], w_out[512,512], b_out[512].
// Round 10: GEMM1 stages x as f32 (swizzled LDS) and converts at frag-read -> cast pass
// deleted. Attention/GEMM2 = R9-proven.
// ws: qkvb bf16[16384,1536] | vT bf16[128,64,1024] | aoutb bf16[16384,512] | wqkvT | woutT

#define QSCALE_ 0.06376541773f        // 512^-0.5 * log2(e)
#define RESCALE_THR_ 8.0f             // log2-domain defer-max threshold

typedef float f32x4 __attribute__((ext_vector_type(4)));
typedef unsigned u32x4 __attribute__((ext_vector_type(4)));
typedef __bf16 bf16x8 __attribute__((ext_vector_type(8)));

static __device__ __forceinline__ ushort bf_bits(float f) {
    unsigned u = __builtin_bit_cast(unsigned, f);
    u += 0x7fffu + ((u >> 16) & 1u);          // RNE
    return (ushort)(u >> 16);
}
static __device__ __forceinline__ unsigned cvt_pk_bf16(float lo, float hi) {
    unsigned d;
    asm("v_cvt_pk_bf16_f32 %0, %1, %2" : "=v"(d) : "v"(lo), "v"(hi));
    return d;
}
static __device__ __forceinline__ float fmax3_(float a, float b, float c) {
    return fmaxf(fmaxf(a, b), c);
}

#define GLDS16(gsrc, ldst)                                                              \
    __builtin_amdgcn_global_load_lds((const __attribute__((address_space(1))) void*)(gsrc), \
                                     (__attribute__((address_space(3))) void*)(ldst), 16, 0, 0)

// ---------------- transpose-cast weights: in[K,N] f32 -> out[N,K] bf16, optional row-scale ----
__global__ __launch_bounds__(256) void transpose_cast(const float* __restrict__ in,
                                                      ushort* __restrict__ out,
                                                      int K, int N, float scale, int scaleRows) {
    __shared__ float t[32][33];
    const int n0 = blockIdx.x * 32, k0 = blockIdx.y * 32;
    const int tx = threadIdx.x & 31, ty = threadIdx.x >> 5;
    for (int i = ty; i < 32; i += 8)
        t[i][tx] = in[(size_t)(k0 + i) * N + n0 + tx];
    __syncthreads();
    for (int i = ty; i < 32; i += 8) {
        const float s = (n0 + i < scaleRows) ? scale : 1.f;
        out[(size_t)(n0 + i) * K + k0 + tx] = bf_bits(t[tx][i] * s);
    }
}

// ---------------- C = A[M,K] @ BT[N,K]^T (+bias), bf16 MFMA ----------------
// AF32: A staged as f32 into swizzled LDS (slot ^ row&7), converted at frag read.
// Cb path: cols >= 1024 (V region) divert to vT[bh=128][dv=64][n=1024] (when VT != null).
template <bool AF32>
__global__ __launch_bounds__(256) void gemm_bf16(const float* __restrict__ Af32,
                                                 const ushort* __restrict__ A,
                                                 const ushort* __restrict__ BT,
                                                 const float* __restrict__ bias,
                                                 float* __restrict__ C,
                                                 ushort* __restrict__ Cb,
                                                 ushort* __restrict__ VT,
                                                 int M, int N, int K) {
    constexpr int BOFF = AF32 ? 16384 : 8192;      // B-tile LDS offset
    __shared__ __align__(16) char lds[BOFF + 8192];
    const int tid = threadIdx.x;
    const int lane = tid & 63;
    const int w = tid >> 6;
    const int wr = w >> 1, wc = w & 1;
    const int fr = lane & 15;
    const int fg = lane >> 4;
    const int rowBase = blockIdx.y * 128;
    const int colBase = blockIdx.x * 128;

    f32x4 acc[4][4] = {};

    for (int k0 = 0; k0 < K; k0 += 32) {
        if constexpr (AF32) {
            // A-tile [128 rows][32 k] f32 = 16KB, 4 rounds, XOR-swizzled source slots
#pragma unroll
            for (int r = 0; r < 4; ++r) {
                const unsigned boff = r * 4096u + w * 1024u + lane * 16u;
                const unsigned row = boff >> 7;               // 128B per row
                const unsigned slot = (boff >> 4) & 7u;
                const unsigned sw = slot ^ (row & 7u);
                GLDS16(Af32 + (size_t)(rowBase + row) * K + k0 + sw * 4,
                       lds + r * 4096 + w * 1024);
            }
        } else {
#pragma unroll
            for (int r = 0; r < 2; ++r) {
                const unsigned boff = r * 4096u + w * 1024u + lane * 16u;
                const unsigned row = boff >> 6;
                const unsigned ke = (boff & 63u) >> 1;
                GLDS16(A + (size_t)(rowBase + row) * K + k0 + ke, lds + r * 4096 + w * 1024);
            }
        }
#pragma unroll
        for (int r = 0; r < 2; ++r) {
            const unsigned boff = r * 4096u + w * 1024u + lane * 16u;
            const unsigned row = boff >> 6;
            const unsigned ke = (boff & 63u) >> 1;
            GLDS16(BT + (size_t)(colBase + row) * K + k0 + ke, lds + BOFF + r * 4096 + w * 1024);
        }
        __syncthreads();

        bf16x8 a_frag[4], b_frag[4];
#pragma unroll
        for (int mi = 0; mi < 4; ++mi) {
            const int row = wr * 64 + mi * 16 + fr;
            if constexpr (AF32) {
                const char* base = lds + row * 128;
                const int r7 = row & 7;
                const f32x4 p0 = *(const f32x4*)(base + (((2 * fg + 0) ^ r7) << 4));
                const f32x4 p1 = *(const f32x4*)(base + (((2 * fg + 1) ^ r7) << 4));
                u32x4 u;
                u[0] = cvt_pk_bf16(p0[0], p0[1]);
                u[1] = cvt_pk_bf16(p0[2], p0[3]);
                u[2] = cvt_pk_bf16(p1[0], p1[1]);
                u[3] = cvt_pk_bf16(p1[2], p1[3]);
                a_frag[mi] = __builtin_bit_cast(bf16x8, u);
            } else {
                a_frag[mi] = *(const bf16x8*)(lds + row * 64 + fg * 16);
            }
        }
#pragma unroll
        for (int ni = 0; ni < 4; ++ni)
            b_frag[ni] = *(const bf16x8*)(lds + BOFF + (wc * 64 + ni * 16 + fr) * 64 + fg * 16);
#pragma unroll
        for (int mi = 0; mi < 4; ++mi)
#pragma unroll
            for (int ni = 0; ni < 4; ++ni)
                acc[mi][ni] = __builtin_amdgcn_mfma_f32_16x16x32_bf16(a_frag[mi], b_frag[ni],
                                                                      acc[mi][ni], 0, 0, 0);
        __syncthreads();
    }

#pragma unroll
    for (int ni = 0; ni < 4; ++ni) {
        const int col = colBase + wc * 64 + ni * 16 + fr;
        const float bv = bias ? bias[col] : 0.f;
#pragma unroll
        for (int mi = 0; mi < 4; ++mi) {
            const int row0 = rowBase + wr * 64 + mi * 16 + fg * 4;
            if (Cb) {
                if (VT && col >= 1024) {
                    const int hd = col - 1024;
                    const size_t vb = ((size_t)((row0 >> 10) * 8 + (hd >> 6)) * 64 + (hd & 63)) * 1024
                                      + (row0 & 1023);
                    ushort4 pk4;
                    pk4.x = bf_bits(acc[mi][ni][0]);
                    pk4.y = bf_bits(acc[mi][ni][1]);
                    pk4.z = bf_bits(acc[mi][ni][2]);
                    pk4.w = bf_bits(acc[mi][ni][3]);
                    *(ushort4*)(VT + vb) = pk4;
                } else {
#pragma unroll
                    for (int q = 0; q < 4; ++q)
                        Cb[(size_t)(row0 + q) * N + col] = bf_bits(acc[mi][ni][q]);
                }
            } else {
#pragma unroll
                for (int q = 0; q < 4; ++q)
                    C[(size_t)(row0 + q) * N + col] = acc[mi][ni][q] + bv;
            }
        }
    }
}

// ---------------- MFMA flash attention, swapped QK^T, in-register softmax (R9-proven) ----
__global__ __launch_bounds__(256) void attn_mfma(const ushort* __restrict__ qkv,
                                                 const ushort* __restrict__ vT,
                                                 ushort* __restrict__ aoutb) {
    __shared__ __align__(16) char lds[40960];  // K:[2]x8KB @0 ; VT:[2]x8KB @16384 ; P: @32768 + w*2048
    const int qt = blockIdx.x;          // 16
    const int bh = blockIdx.y;          // 128
    const int b = bh >> 3, h = bh & 7;
    const int tid = threadIdx.x;
    const int lane = tid & 63;
    const int w = tid >> 6;
    const int fr = lane & 15;
    const int fg = lane >> 4;

    const size_t nbase = (size_t)b * 1024;
    const int qrow0 = qt * 64;

    bf16x8 qf[2];
    {
        const size_t qa = (nbase + qrow0 + w * 16 + fr) * 1536 + h * 64;
        qf[0] = *(const bf16x8*)(qkv + qa + fg * 8);
        qf[1] = *(const bf16x8*)(qkv + qa + 32 + fg * 8);
    }

    bf16x8 onesf;
#pragma unroll
    for (int e = 0; e < 8; ++e) onesf[e] = __builtin_bit_cast(__bf16, (ushort)0x3F80);

    const int srow = w * 16 + (lane >> 3);
    const int slot = lane & 7;
    auto stage = [&](int kt, int buf) {
        char* kd = lds + buf * 8192;
        char* vd = lds + 16384 + buf * 8192;
#pragma unroll
        for (int r = 0; r < 2; ++r) {
            const int row = srow + r * 8;
            const int sw = slot ^ (row & 7);
            GLDS16(qkv + (nbase + kt * 64 + row) * 1536 + 512 + h * 64 + sw * 8,
                   kd + (w * 2 + r) * 1024);
            GLDS16(vT + ((size_t)bh * 64 + row) * 1024 + kt * 64 + sw * 8,
                   vd + (w * 2 + r) * 1024);
        }
    };

    f32x4 o[4] = {};                      // o[dvb]: q = fg*4+r, dv = dvb*16+fr
    f32x4 lacc = {};                      // l[q = fg*4+r]
    float mrow = -INFINITY;               // running max for q = fr (log2 domain)

    stage(0, 0);
    __syncthreads();
    char* const pbase = lds + 32768 + w * 2048;   // per-wave P[16 q][64 k] bf16, swizzled

    auto tile = [&](int kt, int cur) {
        if (kt < 15) stage(kt + 1, cur ^ 1);
        const char* kb = lds + cur * 8192;
        const char* vb = lds + 16384 + cur * 8192;

        // ---- S^T = K Q^T : lane (fr,fg) holds S[k=jb*16+fg*4+r][q=fr] ----
        f32x4 S[4];
        __builtin_amdgcn_s_setprio(1);
#pragma unroll
        for (int jb = 0; jb < 4; ++jb) {
            f32x4 a = {};
#pragma unroll
            for (int s = 0; s < 2; ++s) {
                const int row = jb * 16 + fr;
                const int c = s * 64 + fg * 16;
                const bf16x8 kf = *(const bf16x8*)(kb + row * 128 + (c ^ ((row & 7) << 4)));
                a = __builtin_amdgcn_mfma_f32_16x16x32_bf16(kf, qf[s], a, 0, 0, 0);
            }
            S[jb] = a;
        }
        __builtin_amdgcn_s_setprio(0);

        // ---- row max: max3 tree + cross-fg combine ----
        float tmax = fmax3_(S[0][0], S[0][1], S[0][2]);
        tmax = fmax3_(tmax, S[0][3], S[1][0]);
        tmax = fmax3_(tmax, S[1][1], S[1][2]);
        tmax = fmax3_(tmax, S[1][3], S[2][0]);
        tmax = fmax3_(tmax, S[2][1], S[2][2]);
        tmax = fmax3_(tmax, S[2][3], S[3][0]);
        tmax = fmax3_(tmax, S[3][1], S[3][2]);
        tmax = fmaxf(tmax, S[3][3]);
        tmax = fmaxf(tmax, __shfl_xor(tmax, 16));
        tmax = fmaxf(tmax, __shfl_xor(tmax, 32));

        // ---- defer-max: rescale only when a row grew > THR ----
        if (!__all(tmax - mrow <= RESCALE_THR_)) {
            const float mnew = fmaxf(mrow, tmax);
            const float corr = __builtin_amdgcn_exp2f(mrow - mnew);
            mrow = mnew;
#pragma unroll
            for (int r = 0; r < 4; ++r) {
                const float cr = __shfl(corr, fg * 4 + r);
                lacc[r] *= cr;
#pragma unroll
                for (int dvb = 0; dvb < 4; ++dvb) o[dvb][r] *= cr;
            }
        }

        // ---- P = 2^(S - m), pack (arithmetic 64b build), stage to per-wave LDS ----
#pragma unroll
        for (int jb = 0; jb < 4; ++jb) {
            const unsigned lo = cvt_pk_bf16(__builtin_amdgcn_exp2f(S[jb][0] - mrow),
                                            __builtin_amdgcn_exp2f(S[jb][1] - mrow));
            const unsigned hi = cvt_pk_bf16(__builtin_amdgcn_exp2f(S[jb][2] - mrow),
                                            __builtin_amdgcn_exp2f(S[jb][3] - mrow));
            const unsigned long long pv =
                (unsigned long long)lo | ((unsigned long long)hi << 32);
            *(unsigned long long*)(pbase + fr * 128 +
                                   ((jb * 32 + fg * 8) ^ ((fr & 7) << 4))) = pv;
        }

        // ---- fence: keep P ds_writes ordered before pf ds_reads ----
        asm volatile("" ::: "memory");

        // ---- O += P V ; l += P 1 (row-sum via MFMA) ----
        __builtin_amdgcn_s_setprio(1);
#pragma unroll
        for (int s = 0; s < 2; ++s) {
            const int pc = s * 64 + fg * 16;
            const bf16x8 pf = *(const bf16x8*)(pbase + fr * 128 + (pc ^ ((fr & 7) << 4)));
            lacc = __builtin_amdgcn_mfma_f32_16x16x32_bf16(pf, onesf, lacc, 0, 0, 0);
#pragma unroll
            for (int dvb = 0; dvb < 4; ++dvb) {
                const int vrow = dvb * 16 + fr;
                const bf16x8 vf = *(const bf16x8*)(vb + vrow * 128 + (pc ^ ((vrow & 7) << 4)));
                o[dvb] = __builtin_amdgcn_mfma_f32_16x16x32_bf16(pf, vf, o[dvb], 0, 0, 0);
            }
        }
        __builtin_amdgcn_s_setprio(0);
        __syncthreads();
    };

    for (int kt = 0; kt < 16; kt += 2) {
        tile(kt, 0);
        tile(kt + 1, 1);
    }

    // ---- epilogue: l already indexed by this lane's o-rows (q = fg*4+r) ----
#pragma unroll
    for (int r = 0; r < 4; ++r) {
        const float linv = 1.f / lacc[r];
        const size_t n = nbase + qrow0 + w * 16 + fg * 4 + r;
#pragma unroll
        for (int dvb = 0; dvb < 4; ++dvb)
            aoutb[n * 512 + h * 64 + dvb * 16 + fr] = bf_bits(o[dvb][r] * linv);
    }
}

extern "C" void kernel_launch(void* const* d_in, const int* in_sizes, int n_in,
                              void* d_out, int out_size, void* d_ws, size_t ws_size,
                              hipStream_t stream) {
    const float* x     = (const float*)d_in[0];
    const float* w_qkv = (const float*)d_in[1];
    const float* w_out = (const float*)d_in[2];
    const float* b_out = (const float*)d_in[3];
    float* out = (float*)d_out;

    char* ws = (char*)d_ws;
    ushort* qkvb  = (ushort*)ws;                                  // 48 MiB [16384,1536] (V cols unused)
    ushort* vT    = (ushort*)(ws + 50331648);                     // 16 MiB [128,64,1024]
    ushort* aoutb = (ushort*)(ws + 50331648 + 16777216);          // 16 MiB [16384,512]
    ushort* wqkvT = (ushort*)(ws + 50331648 + 33554432);          // 1.5 MiB
    ushort* woutT = (ushort*)(ws + 50331648 + 33554432 + 1572864);// 0.5 MiB

    const dim3 blk(256);
    // Q-cols (rows 0..511 of wqkvT) pre-scaled by 512^-0.5 * log2(e)
    transpose_cast<<<dim3(1536 / 32, 512 / 32), blk, 0, stream>>>(w_qkv, wqkvT, 512, 1536,
                                                                  QSCALE_, 512);
    transpose_cast<<<dim3(512 / 32, 512 / 32), blk, 0, stream>>>(w_out, woutT, 512, 512,
                                                                 1.f, 0);
    // qkv (bf16) = x @ w_qkv ; V columns divert to vT ; x read as f32 (cast fused in LDS path)
    gemm_bf16<true><<<dim3(12, 128), blk, 0, stream>>>(x, nullptr, wqkvT, nullptr,
                                                       nullptr, qkvb, vT, 16384, 1536, 512);
    // attention (64-row q-tiles)
    attn_mfma<<<dim3(16, 128), blk, 0, stream>>>(qkvb, vT, aoutb);
    // out = aout @ w_out + b_out (f32)
    gemm_bf16<false><<<dim3(4, 128), blk, 0, stream>>>(nullptr, aoutb, woutT, b_out,
                                                       out, nullptr, nullptr, 16384, 512, 512);
}

// Round 11
// 145.252 us; speedup vs baseline: 1.0731x; 1.0731x over previous
//
#include <hip/hip_runtime.h>
#include <math.h>

// MHSA forward. x[16,1024,512]f32, w_qkv[512,1536], w_out[512,512], b_out[512].
// Round 11: R9 base; GEMMs switched to double-buffered single-barrier prefetch
// (stage t+1 before compute t, one __syncthreads per k-step — same schedule as attn).
// ws: qkvb bf16[16384,1536] | vT bf16[128,64,1024] | xb/aoutb bf16[16384,512] | wqkvT | woutT

#define QSCALE_ 0.06376541773f        // 512^-0.5 * log2(e)
#define RESCALE_THR_ 8.0f             // log2-domain defer-max threshold

typedef float f32x4 __attribute__((ext_vector_type(4)));
typedef __bf16 bf16x8 __attribute__((ext_vector_type(8)));

static __device__ __forceinline__ ushort bf_bits(float f) {
    unsigned u = __builtin_bit_cast(unsigned, f);
    u += 0x7fffu + ((u >> 16) & 1u);          // RNE
    return (ushort)(u >> 16);
}
static __device__ __forceinline__ unsigned cvt_pk_bf16(float lo, float hi) {
    unsigned d;
    asm("v_cvt_pk_bf16_f32 %0, %1, %2" : "=v"(d) : "v"(lo), "v"(hi));
    return d;
}
static __device__ __forceinline__ float fmax3_(float a, float b, float c) {
    return fmaxf(fmaxf(a, b), c);
}

#define GLDS16(gsrc, ldst)                                                              \
    __builtin_amdgcn_global_load_lds((const __attribute__((address_space(1))) void*)(gsrc), \
                                     (__attribute__((address_space(3))) void*)(ldst), 16, 0, 0)

// ---------------- cast f32 -> bf16 ----------------
__global__ __launch_bounds__(256) void cast_bf16(const float* __restrict__ in,
                                                 ushort* __restrict__ out, int n4) {
    const int i = blockIdx.x * 256 + threadIdx.x;
    if (i >= n4) return;
    const float4 v = ((const float4*)in)[i];
    ushort4 o;
    o.x = bf_bits(v.x); o.y = bf_bits(v.y); o.z = bf_bits(v.z); o.w = bf_bits(v.w);
    ((ushort4*)out)[i] = o;
}

// ---------------- transpose-cast weights: in[K,N] f32 -> out[N,K] bf16, optional row-scale ----
__global__ __launch_bounds__(256) void transpose_cast(const float* __restrict__ in,
                                                      ushort* __restrict__ out,
                                                      int K, int N, float scale, int scaleRows) {
    __shared__ float t[32][33];
    const int n0 = blockIdx.x * 32, k0 = blockIdx.y * 32;
    const int tx = threadIdx.x & 31, ty = threadIdx.x >> 5;
    for (int i = ty; i < 32; i += 8)
        t[i][tx] = in[(size_t)(k0 + i) * N + n0 + tx];
    __syncthreads();
    for (int i = ty; i < 32; i += 8) {
        const float s = (n0 + i < scaleRows) ? scale : 1.f;
        out[(size_t)(n0 + i) * K + k0 + tx] = bf_bits(t[tx][i] * s);
    }
}

// ---------------- C = A[M,K] @ BT[N,K]^T (+bias), bf16 MFMA, double-buffered ----------------
// Single barrier per k-step: stage(t+1) issued before compute(t); syncthreads at step end
// drains the prefetch and closes the read window. LDS 32KB: A[2]x8KB @0, B[2]x8KB @16384.
// Cb path: cols >= 1024 (V region) divert to vT[bh=128][dv=64][n=1024] (when VT != null).
__global__ __launch_bounds__(256) void gemm_bf16(const ushort* __restrict__ A,
                                                 const ushort* __restrict__ BT,
                                                 const float* __restrict__ bias,
                                                 float* __restrict__ C,
                                                 ushort* __restrict__ Cb,
                                                 ushort* __restrict__ VT,
                                                 int M, int N, int K) {
    __shared__ __align__(16) char lds[32768];
    const int tid = threadIdx.x;
    const int lane = tid & 63;
    const int w = tid >> 6;
    const int wr = w >> 1, wc = w & 1;
    const int fr = lane & 15;
    const int fg = lane >> 4;
    const int rowBase = blockIdx.y * 128;
    const int colBase = blockIdx.x * 128;

    auto stageG = [&](int k0, int buf) {
#pragma unroll
        for (int r = 0; r < 2; ++r) {
            const unsigned boff = r * 4096u + w * 1024u + lane * 16u;
            const unsigned row = boff >> 6;
            const unsigned ke = (boff & 63u) >> 1;
            GLDS16(A + (size_t)(rowBase + row) * K + k0 + ke,
                   lds + buf * 8192 + r * 4096 + w * 1024);
            GLDS16(BT + (size_t)(colBase + row) * K + k0 + ke,
                   lds + 16384 + buf * 8192 + r * 4096 + w * 1024);
        }
    };

    f32x4 acc[4][4] = {};

    stageG(0, 0);
    __syncthreads();
    int cur = 0;
    const int nsteps = K / 32;

    for (int s = 0; s < nsteps; ++s) {
        if (s + 1 < nsteps) stageG((s + 1) * 32, cur ^ 1);
        const char* ab = lds + cur * 8192;
        const char* bb = lds + 16384 + cur * 8192;

        bf16x8 a_frag[4], b_frag[4];
#pragma unroll
        for (int mi = 0; mi < 4; ++mi)
            a_frag[mi] = *(const bf16x8*)(ab + (wr * 64 + mi * 16 + fr) * 64 + fg * 16);
#pragma unroll
        for (int ni = 0; ni < 4; ++ni)
            b_frag[ni] = *(const bf16x8*)(bb + (wc * 64 + ni * 16 + fr) * 64 + fg * 16);
#pragma unroll
        for (int mi = 0; mi < 4; ++mi)
#pragma unroll
            for (int ni = 0; ni < 4; ++ni)
                acc[mi][ni] = __builtin_amdgcn_mfma_f32_16x16x32_bf16(a_frag[mi], b_frag[ni],
                                                                      acc[mi][ni], 0, 0, 0);
        __syncthreads();
        cur ^= 1;
    }

#pragma unroll
    for (int ni = 0; ni < 4; ++ni) {
        const int col = colBase + wc * 64 + ni * 16 + fr;
        const float bv = bias ? bias[col] : 0.f;
#pragma unroll
        for (int mi = 0; mi < 4; ++mi) {
            const int row0 = rowBase + wr * 64 + mi * 16 + fg * 4;
            if (Cb) {
                if (VT && col >= 1024) {
                    const int hd = col - 1024;
                    const size_t vb = ((size_t)((row0 >> 10) * 8 + (hd >> 6)) * 64 + (hd & 63)) * 1024
                                      + (row0 & 1023);
                    ushort4 pk4;
                    pk4.x = bf_bits(acc[mi][ni][0]);
                    pk4.y = bf_bits(acc[mi][ni][1]);
                    pk4.z = bf_bits(acc[mi][ni][2]);
                    pk4.w = bf_bits(acc[mi][ni][3]);
                    *(ushort4*)(VT + vb) = pk4;
                } else {
#pragma unroll
                    for (int q = 0; q < 4; ++q)
                        Cb[(size_t)(row0 + q) * N + col] = bf_bits(acc[mi][ni][q]);
                }
            } else {
#pragma unroll
                for (int q = 0; q < 4; ++q)
                    C[(size_t)(row0 + q) * N + col] = acc[mi][ni][q] + bv;
            }
        }
    }
}

// ---------------- MFMA flash attention, swapped QK^T, in-register softmax (R9-proven) ----
__global__ __launch_bounds__(256) void attn_mfma(const ushort* __restrict__ qkv,
                                                 const ushort* __restrict__ vT,
                                                 ushort* __restrict__ aoutb) {
    __shared__ __align__(16) char lds[40960];  // K:[2]x8KB @0 ; VT:[2]x8KB @16384 ; P: @32768 + w*2048
    const int qt = blockIdx.x;          // 16
    const int bh = blockIdx.y;          // 128
    const int b = bh >> 3, h = bh & 7;
    const int tid = threadIdx.x;
    const int lane = tid & 63;
    const int w = tid >> 6;
    const int fr = lane & 15;
    const int fg = lane >> 4;

    const size_t nbase = (size_t)b * 1024;
    const int qrow0 = qt * 64;

    bf16x8 qf[2];
    {
        const size_t qa = (nbase + qrow0 + w * 16 + fr) * 1536 + h * 64;
        qf[0] = *(const bf16x8*)(qkv + qa + fg * 8);
        qf[1] = *(const bf16x8*)(qkv + qa + 32 + fg * 8);
    }

    bf16x8 onesf;
#pragma unroll
    for (int e = 0; e < 8; ++e) onesf[e] = __builtin_bit_cast(__bf16, (ushort)0x3F80);

    const int srow = w * 16 + (lane >> 3);
    const int slot = lane & 7;
    auto stage = [&](int kt, int buf) {
        char* kd = lds + buf * 8192;
        char* vd = lds + 16384 + buf * 8192;
#pragma unroll
        for (int r = 0; r < 2; ++r) {
            const int row = srow + r * 8;
            const int sw = slot ^ (row & 7);
            GLDS16(qkv + (nbase + kt * 64 + row) * 1536 + 512 + h * 64 + sw * 8,
                   kd + (w * 2 + r) * 1024);
            GLDS16(vT + ((size_t)bh * 64 + row) * 1024 + kt * 64 + sw * 8,
                   vd + (w * 2 + r) * 1024);
        }
    };

    f32x4 o[4] = {};                      // o[dvb]: q = fg*4+r, dv = dvb*16+fr
    f32x4 lacc = {};                      // l[q = fg*4+r]
    float mrow = -INFINITY;               // running max for q = fr (log2 domain)

    stage(0, 0);
    __syncthreads();
    char* const pbase = lds + 32768 + w * 2048;   // per-wave P[16 q][64 k] bf16, swizzled

    auto tile = [&](int kt, int cur) {
        if (kt < 15) stage(kt + 1, cur ^ 1);
        const char* kb = lds + cur * 8192;
        const char* vb = lds + 16384 + cur * 8192;

        // ---- S^T = K Q^T : lane (fr,fg) holds S[k=jb*16+fg*4+r][q=fr] ----
        f32x4 S[4];
        __builtin_amdgcn_s_setprio(1);
#pragma unroll
        for (int jb = 0; jb < 4; ++jb) {
            f32x4 a = {};
#pragma unroll
            for (int s = 0; s < 2; ++s) {
                const int row = jb * 16 + fr;
                const int c = s * 64 + fg * 16;
                const bf16x8 kf = *(const bf16x8*)(kb + row * 128 + (c ^ ((row & 7) << 4)));
                a = __builtin_amdgcn_mfma_f32_16x16x32_bf16(kf, qf[s], a, 0, 0, 0);
            }
            S[jb] = a;
        }
        __builtin_amdgcn_s_setprio(0);

        // ---- row max: max3 tree + cross-fg combine ----
        float tmax = fmax3_(S[0][0], S[0][1], S[0][2]);
        tmax = fmax3_(tmax, S[0][3], S[1][0]);
        tmax = fmax3_(tmax, S[1][1], S[1][2]);
        tmax = fmax3_(tmax, S[1][3], S[2][0]);
        tmax = fmax3_(tmax, S[2][1], S[2][2]);
        tmax = fmax3_(tmax, S[2][3], S[3][0]);
        tmax = fmax3_(tmax, S[3][1], S[3][2]);
        tmax = fmaxf(tmax, S[3][3]);
        tmax = fmaxf(tmax, __shfl_xor(tmax, 16));
        tmax = fmaxf(tmax, __shfl_xor(tmax, 32));

        // ---- defer-max: rescale only when a row grew > THR ----
        if (!__all(tmax - mrow <= RESCALE_THR_)) {
            const float mnew = fmaxf(mrow, tmax);
            const float corr = __builtin_amdgcn_exp2f(mrow - mnew);
            mrow = mnew;
#pragma unroll
            for (int r = 0; r < 4; ++r) {
                const float cr = __shfl(corr, fg * 4 + r);
                lacc[r] *= cr;
#pragma unroll
                for (int dvb = 0; dvb < 4; ++dvb) o[dvb][r] *= cr;
            }
        }

        // ---- P = 2^(S - m), pack (arithmetic 64b build), stage to per-wave LDS ----
#pragma unroll
        for (int jb = 0; jb < 4; ++jb) {
            const unsigned lo = cvt_pk_bf16(__builtin_amdgcn_exp2f(S[jb][0] - mrow),
                                            __builtin_amdgcn_exp2f(S[jb][1] - mrow));
            const unsigned hi = cvt_pk_bf16(__builtin_amdgcn_exp2f(S[jb][2] - mrow),
                                            __builtin_amdgcn_exp2f(S[jb][3] - mrow));
            const unsigned long long pv =
                (unsigned long long)lo | ((unsigned long long)hi << 32);
            *(unsigned long long*)(pbase + fr * 128 +
                                   ((jb * 32 + fg * 8) ^ ((fr & 7) << 4))) = pv;
        }

        // ---- fence: keep P ds_writes ordered before pf ds_reads ----
        asm volatile("" ::: "memory");

        // ---- O += P V ; l += P 1 (row-sum via MFMA) ----
        __builtin_amdgcn_s_setprio(1);
#pragma unroll
        for (int s = 0; s < 2; ++s) {
            const int pc = s * 64 + fg * 16;
            const bf16x8 pf = *(const bf16x8*)(pbase + fr * 128 + (pc ^ ((fr & 7) << 4)));
            lacc = __builtin_amdgcn_mfma_f32_16x16x32_bf16(pf, onesf, lacc, 0, 0, 0);
#pragma unroll
            for (int dvb = 0; dvb < 4; ++dvb) {
                const int vrow = dvb * 16 + fr;
                const bf16x8 vf = *(const bf16x8*)(vb + vrow * 128 + (pc ^ ((vrow & 7) << 4)));
                o[dvb] = __builtin_amdgcn_mfma_f32_16x16x32_bf16(pf, vf, o[dvb], 0, 0, 0);
            }
        }
        __builtin_amdgcn_s_setprio(0);
        __syncthreads();
    };

    for (int kt = 0; kt < 16; kt += 2) {
        tile(kt, 0);
        tile(kt + 1, 1);
    }

    // ---- epilogue: l already indexed by this lane's o-rows (q = fg*4+r) ----
#pragma unroll
    for (int r = 0; r < 4; ++r) {
        const float linv = 1.f / lacc[r];
        const size_t n = nbase + qrow0 + w * 16 + fg * 4 + r;
#pragma unroll
        for (int dvb = 0; dvb < 4; ++dvb)
            aoutb[n * 512 + h * 64 + dvb * 16 + fr] = bf_bits(o[dvb][r] * linv);
    }
}

extern "C" void kernel_launch(void* const* d_in, const int* in_sizes, int n_in,
                              void* d_out, int out_size, void* d_ws, size_t ws_size,
                              hipStream_t stream) {
    const float* x     = (const float*)d_in[0];
    const float* w_qkv = (const float*)d_in[1];
    const float* w_out = (const float*)d_in[2];
    const float* b_out = (const float*)d_in[3];
    float* out = (float*)d_out;

    char* ws = (char*)d_ws;
    ushort* qkvb  = (ushort*)ws;                                  // 48 MiB [16384,1536] (V cols unused)
    ushort* vT    = (ushort*)(ws + 50331648);                     // 16 MiB [128,64,1024]
    ushort* xb    = (ushort*)(ws + 50331648 + 16777216);          // 16 MiB
    ushort* aoutb = xb;                                           // aliased (xb dead after GEMM1)
    ushort* wqkvT = (ushort*)(ws + 50331648 + 33554432);          // 1.5 MiB
    ushort* woutT = (ushort*)(ws + 50331648 + 33554432 + 1572864);// 0.5 MiB

    const dim3 blk(256);
    cast_bf16<<<dim3(8388608 / 4 / 256), blk, 0, stream>>>(x, xb, 8388608 / 4);
    // Q-cols (rows 0..511 of wqkvT) pre-scaled by 512^-0.5 * log2(e)
    transpose_cast<<<dim3(1536 / 32, 512 / 32), blk, 0, stream>>>(w_qkv, wqkvT, 512, 1536,
                                                                  QSCALE_, 512);
    transpose_cast<<<dim3(512 / 32, 512 / 32), blk, 0, stream>>>(w_out, woutT, 512, 512,
                                                                 1.f, 0);
    // qkv (bf16) = x @ w_qkv ; V columns divert to vT
    gemm_bf16<<<dim3(12, 128), blk, 0, stream>>>(xb, wqkvT, nullptr, nullptr, qkvb, vT,
                                                 16384, 1536, 512);
    // attention (64-row q-tiles)
    attn_mfma<<<dim3(16, 128), blk, 0, stream>>>(qkvb, vT, aoutb);
    // out = aout @ w_out + b_out (f32)
    gemm_bf16<<<dim3(4, 128), blk, 0, stream>>>(aoutb, woutT, b_out, out, nullptr, nullptr,
                                                16384, 512, 512);
}

// Round 12
// 136.032 us; speedup vs baseline: 1.1459x; 1.0678x over previous
//
#include <hip/hip_runtime.h>
#include <math.h>

// MHSA forward. x[16,1024,512]f32, w_qkv[512,1536], w_out[512,512], b_out[512].
// Round 12: XCD-aware bijective swizzle (T1) on attention + both GEMMs (1-D grids,
// logical = (bid&7)*cpx + bid>>3); transposes merged into one dispatch. Else = R11.
// ws: qkvb bf16[16384,1536] | vT bf16[128,64,1024] | xb/aoutb bf16[16384,512] | wqkvT | woutT

#define QSCALE_ 0.06376541773f        // 512^-0.5 * log2(e)
#define RESCALE_THR_ 8.0f             // log2-domain defer-max threshold

typedef float f32x4 __attribute__((ext_vector_type(4)));
typedef __bf16 bf16x8 __attribute__((ext_vector_type(8)));

static __device__ __forceinline__ ushort bf_bits(float f) {
    unsigned u = __builtin_bit_cast(unsigned, f);
    u += 0x7fffu + ((u >> 16) & 1u);          // RNE
    return (ushort)(u >> 16);
}
static __device__ __forceinline__ unsigned cvt_pk_bf16(float lo, float hi) {
    unsigned d;
    asm("v_cvt_pk_bf16_f32 %0, %1, %2" : "=v"(d) : "v"(lo), "v"(hi));
    return d;
}
static __device__ __forceinline__ float fmax3_(float a, float b, float c) {
    return fmaxf(fmaxf(a, b), c);
}
// bijective XCD swizzle: consecutive logical ids land on the same XCD (requires nwg%8==0)
static __device__ __forceinline__ int xcd_logical(int bid, int nwg) {
    return (bid & 7) * (nwg >> 3) + (bid >> 3);
}

#define GLDS16(gsrc, ldst)                                                              \
    __builtin_amdgcn_global_load_lds((const __attribute__((address_space(1))) void*)(gsrc), \
                                     (__attribute__((address_space(3))) void*)(ldst), 16, 0, 0)

// ---------------- cast f32 -> bf16 ----------------
__global__ __launch_bounds__(256) void cast_bf16(const float* __restrict__ in,
                                                 ushort* __restrict__ out, int n4) {
    const int i = blockIdx.x * 256 + threadIdx.x;
    if (i >= n4) return;
    const float4 v = ((const float4*)in)[i];
    ushort4 o;
    o.x = bf_bits(v.x); o.y = bf_bits(v.y); o.z = bf_bits(v.z); o.w = bf_bits(v.w);
    ((ushort4*)out)[i] = o;
}

// ---------------- both weight transposes in one dispatch ----------------
// blocks [0,768): w_qkv [512,1536] -> wqkvT [1536,512] (Q-rows scaled);
// blocks [768,1024): w_out [512,512] -> woutT [512,512].
__global__ __launch_bounds__(256) void transpose_cast2(const float* __restrict__ wqkv,
                                                       ushort* __restrict__ wqkvT,
                                                       const float* __restrict__ wout,
                                                       ushort* __restrict__ woutT) {
    __shared__ float t[32][33];
    const int tx = threadIdx.x & 31, ty = threadIdx.x >> 5;
    const float* in;
    ushort* out;
    int n0, k0, N;
    float scale;
    int scaleRows;
    if (blockIdx.x < 768) {
        in = wqkv; out = wqkvT; N = 1536;
        n0 = (blockIdx.x % 48) * 32; k0 = (blockIdx.x / 48) * 32;
        scale = QSCALE_; scaleRows = 512;
    } else {
        in = wout; out = woutT; N = 512;
        const int b2 = blockIdx.x - 768;
        n0 = (b2 % 16) * 32; k0 = (b2 / 16) * 32;
        scale = 1.f; scaleRows = 0;
    }
    for (int i = ty; i < 32; i += 8)
        t[i][tx] = in[(size_t)(k0 + i) * N + n0 + tx];
    __syncthreads();
    for (int i = ty; i < 32; i += 8) {
        const float s = (n0 + i < scaleRows) ? scale : 1.f;
        out[(size_t)(n0 + i) * 512 + k0 + tx] = bf_bits(t[tx][i] * s);
    }
}

// ---------------- C = A[M,K] @ BT[N,K]^T (+bias), bf16 MFMA, double-buffered ----------------
// 1-D grid (nwg = (N/128)*(M/128)), XCD-swizzled: logical%nx = col tile, logical/nx = row tile.
// Cb path: cols >= 1024 (V region) divert to vT[bh=128][dv=64][n=1024] (when VT != null).
__global__ __launch_bounds__(256) void gemm_bf16(const ushort* __restrict__ A,
                                                 const ushort* __restrict__ BT,
                                                 const float* __restrict__ bias,
                                                 float* __restrict__ C,
                                                 ushort* __restrict__ Cb,
                                                 ushort* __restrict__ VT,
                                                 int M, int N, int K, int nx) {
    __shared__ __align__(16) char lds[32768];
    const int logical = xcd_logical(blockIdx.x, gridDim.x);
    const int bx = logical % nx;
    const int by = logical / nx;
    const int tid = threadIdx.x;
    const int lane = tid & 63;
    const int w = tid >> 6;
    const int wr = w >> 1, wc = w & 1;
    const int fr = lane & 15;
    const int fg = lane >> 4;
    const int rowBase = by * 128;
    const int colBase = bx * 128;

    auto stageG = [&](int k0, int buf) {
#pragma unroll
        for (int r = 0; r < 2; ++r) {
            const unsigned boff = r * 4096u + w * 1024u + lane * 16u;
            const unsigned row = boff >> 6;
            const unsigned ke = (boff & 63u) >> 1;
            GLDS16(A + (size_t)(rowBase + row) * K + k0 + ke,
                   lds + buf * 8192 + r * 4096 + w * 1024);
            GLDS16(BT + (size_t)(colBase + row) * K + k0 + ke,
                   lds + 16384 + buf * 8192 + r * 4096 + w * 1024);
        }
    };

    f32x4 acc[4][4] = {};

    stageG(0, 0);
    __syncthreads();
    int cur = 0;
    const int nsteps = K / 32;

    for (int s = 0; s < nsteps; ++s) {
        if (s + 1 < nsteps) stageG((s + 1) * 32, cur ^ 1);
        const char* ab = lds + cur * 8192;
        const char* bb = lds + 16384 + cur * 8192;

        bf16x8 a_frag[4], b_frag[4];
#pragma unroll
        for (int mi = 0; mi < 4; ++mi)
            a_frag[mi] = *(const bf16x8*)(ab + (wr * 64 + mi * 16 + fr) * 64 + fg * 16);
#pragma unroll
        for (int ni = 0; ni < 4; ++ni)
            b_frag[ni] = *(const bf16x8*)(bb + (wc * 64 + ni * 16 + fr) * 64 + fg * 16);
#pragma unroll
        for (int mi = 0; mi < 4; ++mi)
#pragma unroll
            for (int ni = 0; ni < 4; ++ni)
                acc[mi][ni] = __builtin_amdgcn_mfma_f32_16x16x32_bf16(a_frag[mi], b_frag[ni],
                                                                      acc[mi][ni], 0, 0, 0);
        __syncthreads();
        cur ^= 1;
    }

#pragma unroll
    for (int ni = 0; ni < 4; ++ni) {
        const int col = colBase + wc * 64 + ni * 16 + fr;
        const float bv = bias ? bias[col] : 0.f;
#pragma unroll
        for (int mi = 0; mi < 4; ++mi) {
            const int row0 = rowBase + wr * 64 + mi * 16 + fg * 4;
            if (Cb) {
                if (VT && col >= 1024) {
                    const int hd = col - 1024;
                    const size_t vb = ((size_t)((row0 >> 10) * 8 + (hd >> 6)) * 64 + (hd & 63)) * 1024
                                      + (row0 & 1023);
                    ushort4 pk4;
                    pk4.x = bf_bits(acc[mi][ni][0]);
                    pk4.y = bf_bits(acc[mi][ni][1]);
                    pk4.z = bf_bits(acc[mi][ni][2]);
                    pk4.w = bf_bits(acc[mi][ni][3]);
                    *(ushort4*)(VT + vb) = pk4;
                } else {
#pragma unroll
                    for (int q = 0; q < 4; ++q)
                        Cb[(size_t)(row0 + q) * N + col] = bf_bits(acc[mi][ni][q]);
                }
            } else {
#pragma unroll
                for (int q = 0; q < 4; ++q)
                    C[(size_t)(row0 + q) * N + col] = acc[mi][ni][q] + bv;
            }
        }
    }
}

// ---------------- MFMA flash attention, swapped QK^T, in-register softmax ----------------
// 1-D grid 2048, XCD-swizzled: logical&15 = qt (fast), logical>>4 = bh -> all 16 qt-WGs
// of one (b,h) land on the same XCD; K/V (256KB) fetched ~once per XCD L2.
__global__ __launch_bounds__(256) void attn_mfma(const ushort* __restrict__ qkv,
                                                 const ushort* __restrict__ vT,
                                                 ushort* __restrict__ aoutb) {
    __shared__ __align__(16) char lds[40960];  // K:[2]x8KB @0 ; VT:[2]x8KB @16384 ; P: @32768 + w*2048
    const int logical = xcd_logical(blockIdx.x, gridDim.x);
    const int qt = logical & 15;
    const int bh = logical >> 4;
    const int b = bh >> 3, h = bh & 7;
    const int tid = threadIdx.x;
    const int lane = tid & 63;
    const int w = tid >> 6;
    const int fr = lane & 15;
    const int fg = lane >> 4;

    const size_t nbase = (size_t)b * 1024;
    const int qrow0 = qt * 64;

    bf16x8 qf[2];
    {
        const size_t qa = (nbase + qrow0 + w * 16 + fr) * 1536 + h * 64;
        qf[0] = *(const bf16x8*)(qkv + qa + fg * 8);
        qf[1] = *(const bf16x8*)(qkv + qa + 32 + fg * 8);
    }

    bf16x8 onesf;
#pragma unroll
    for (int e = 0; e < 8; ++e) onesf[e] = __builtin_bit_cast(__bf16, (ushort)0x3F80);

    const int srow = w * 16 + (lane >> 3);
    const int slot = lane & 7;
    auto stage = [&](int kt, int buf) {
        char* kd = lds + buf * 8192;
        char* vd = lds + 16384 + buf * 8192;
#pragma unroll
        for (int r = 0; r < 2; ++r) {
            const int row = srow + r * 8;
            const int sw = slot ^ (row & 7);
            GLDS16(qkv + (nbase + kt * 64 + row) * 1536 + 512 + h * 64 + sw * 8,
                   kd + (w * 2 + r) * 1024);
            GLDS16(vT + ((size_t)bh * 64 + row) * 1024 + kt * 64 + sw * 8,
                   vd + (w * 2 + r) * 1024);
        }
    };

    f32x4 o[4] = {};                      // o[dvb]: q = fg*4+r, dv = dvb*16+fr
    f32x4 lacc = {};                      // l[q = fg*4+r]
    float mrow = -INFINITY;               // running max for q = fr (log2 domain)

    stage(0, 0);
    __syncthreads();
    char* const pbase = lds + 32768 + w * 2048;   // per-wave P[16 q][64 k] bf16, swizzled

    auto tile = [&](int kt, int cur) {
        if (kt < 15) stage(kt + 1, cur ^ 1);
        const char* kb = lds + cur * 8192;
        const char* vb = lds + 16384 + cur * 8192;

        // ---- S^T = K Q^T : lane (fr,fg) holds S[k=jb*16+fg*4+r][q=fr] ----
        f32x4 S[4];
        __builtin_amdgcn_s_setprio(1);
#pragma unroll
        for (int jb = 0; jb < 4; ++jb) {
            f32x4 a = {};
#pragma unroll
            for (int s = 0; s < 2; ++s) {
                const int row = jb * 16 + fr;
                const int c = s * 64 + fg * 16;
                const bf16x8 kf = *(const bf16x8*)(kb + row * 128 + (c ^ ((row & 7) << 4)));
                a = __builtin_amdgcn_mfma_f32_16x16x32_bf16(kf, qf[s], a, 0, 0, 0);
            }
            S[jb] = a;
        }
        __builtin_amdgcn_s_setprio(0);

        // ---- row max: max3 tree + cross-fg combine ----
        float tmax = fmax3_(S[0][0], S[0][1], S[0][2]);
        tmax = fmax3_(tmax, S[0][3], S[1][0]);
        tmax = fmax3_(tmax, S[1][1], S[1][2]);
        tmax = fmax3_(tmax, S[1][3], S[2][0]);
        tmax = fmax3_(tmax, S[2][1], S[2][2]);
        tmax = fmax3_(tmax, S[2][3], S[3][0]);
        tmax = fmax3_(tmax, S[3][1], S[3][2]);
        tmax = fmaxf(tmax, S[3][3]);
        tmax = fmaxf(tmax, __shfl_xor(tmax, 16));
        tmax = fmaxf(tmax, __shfl_xor(tmax, 32));

        // ---- defer-max: rescale only when a row grew > THR ----
        if (!__all(tmax - mrow <= RESCALE_THR_)) {
            const float mnew = fmaxf(mrow, tmax);
            const float corr = __builtin_amdgcn_exp2f(mrow - mnew);
            mrow = mnew;
#pragma unroll
            for (int r = 0; r < 4; ++r) {
                const float cr = __shfl(corr, fg * 4 + r);
                lacc[r] *= cr;
#pragma unroll
                for (int dvb = 0; dvb < 4; ++dvb) o[dvb][r] *= cr;
            }
        }

        // ---- P = 2^(S - m), pack (arithmetic 64b build), stage to per-wave LDS ----
#pragma unroll
        for (int jb = 0; jb < 4; ++jb) {
            const unsigned lo = cvt_pk_bf16(__builtin_amdgcn_exp2f(S[jb][0] - mrow),
                                            __builtin_amdgcn_exp2f(S[jb][1] - mrow));
            const unsigned hi = cvt_pk_bf16(__builtin_amdgcn_exp2f(S[jb][2] - mrow),
                                            __builtin_amdgcn_exp2f(S[jb][3] - mrow));
            const unsigned long long pv =
                (unsigned long long)lo | ((unsigned long long)hi << 32);
            *(unsigned long long*)(pbase + fr * 128 +
                                   ((jb * 32 + fg * 8) ^ ((fr & 7) << 4))) = pv;
        }

        // ---- fence: keep P ds_writes ordered before pf ds_reads ----
        asm volatile("" ::: "memory");

        // ---- O += P V ; l += P 1 (row-sum via MFMA) ----
        __builtin_amdgcn_s_setprio(1);
#pragma unroll
        for (int s = 0; s < 2; ++s) {
            const int pc = s * 64 + fg * 16;
            const bf16x8 pf = *(const bf16x8*)(pbase + fr * 128 + (pc ^ ((fr & 7) << 4)));
            lacc = __builtin_amdgcn_mfma_f32_16x16x32_bf16(pf, onesf, lacc, 0, 0, 0);
#pragma unroll
            for (int dvb = 0; dvb < 4; ++dvb) {
                const int vrow = dvb * 16 + fr;
                const bf16x8 vf = *(const bf16x8*)(vb + vrow * 128 + (pc ^ ((vrow & 7) << 4)));
                o[dvb] = __builtin_amdgcn_mfma_f32_16x16x32_bf16(pf, vf, o[dvb], 0, 0, 0);
            }
        }
        __builtin_amdgcn_s_setprio(0);
        __syncthreads();
    };

    for (int kt = 0; kt < 16; kt += 2) {
        tile(kt, 0);
        tile(kt + 1, 1);
    }

    // ---- epilogue: l already indexed by this lane's o-rows (q = fg*4+r) ----
#pragma unroll
    for (int r = 0; r < 4; ++r) {
        const float linv = 1.f / lacc[r];
        const size_t n = nbase + qrow0 + w * 16 + fg * 4 + r;
#pragma unroll
        for (int dvb = 0; dvb < 4; ++dvb)
            aoutb[n * 512 + h * 64 + dvb * 16 + fr] = bf_bits(o[dvb][r] * linv);
    }
}

extern "C" void kernel_launch(void* const* d_in, const int* in_sizes, int n_in,
                              void* d_out, int out_size, void* d_ws, size_t ws_size,
                              hipStream_t stream) {
    const float* x     = (const float*)d_in[0];
    const float* w_qkv = (const float*)d_in[1];
    const float* w_out = (const float*)d_in[2];
    const float* b_out = (const float*)d_in[3];
    float* out = (float*)d_out;

    char* ws = (char*)d_ws;
    ushort* qkvb  = (ushort*)ws;                                  // 48 MiB [16384,1536] (V cols unused)
    ushort* vT    = (ushort*)(ws + 50331648);                     // 16 MiB [128,64,1024]
    ushort* xb    = (ushort*)(ws + 50331648 + 16777216);          // 16 MiB
    ushort* aoutb = xb;                                           // aliased (xb dead after GEMM1)
    ushort* wqkvT = (ushort*)(ws + 50331648 + 33554432);          // 1.5 MiB
    ushort* woutT = (ushort*)(ws + 50331648 + 33554432 + 1572864);// 0.5 MiB

    const dim3 blk(256);
    cast_bf16<<<dim3(8388608 / 4 / 256), blk, 0, stream>>>(x, xb, 8388608 / 4);
    transpose_cast2<<<dim3(1024), blk, 0, stream>>>(w_qkv, wqkvT, w_out, woutT);
    // qkv (bf16) = x @ w_qkv ; V columns divert to vT
    gemm_bf16<<<dim3(1536), blk, 0, stream>>>(xb, wqkvT, nullptr, nullptr, qkvb, vT,
                                              16384, 1536, 512, 12);
    // attention (64-row q-tiles), XCD-swizzled
    attn_mfma<<<dim3(2048), blk, 0, stream>>>(qkvb, vT, aoutb);
    // out = aout @ w_out + b_out (f32)
    gemm_bf16<<<dim3(512), blk, 0, stream>>>(aoutb, woutT, b_out, out, nullptr, nullptr,
                                             16384, 512, 512, 4);
}

// Round 14
// 134.632 us; speedup vs baseline: 1.1578x; 1.0104x over previous
//
#include <hip/hip_runtime.h>
#include <math.h>

// MHSA forward. x[16,1024,512]f32, w_qkv[512,1536], w_out[512,512], b_out[512].
// Round 14: R12 verbatim (proven 136us: XCD swizzle, dbuf GEMMs stage-first, R9 attn
// schedule stage-first) + single merged prep dispatch (cast + both transposes).
// NOTE: attn/gemm schedules are order-sensitive (R13 post-mortem) — do not reorder
// stage() relative to compute phases.
// ws: qkvb bf16[16384,1536] | vT bf16[128,64,1024] | xb/aoutb bf16[16384,512] | wqkvT | woutT

#define QSCALE_ 0.06376541773f        // 512^-0.5 * log2(e)
#define RESCALE_THR_ 8.0f             // log2-domain defer-max threshold

typedef float f32x4 __attribute__((ext_vector_type(4)));
typedef __bf16 bf16x8 __attribute__((ext_vector_type(8)));

static __device__ __forceinline__ ushort bf_bits(float f) {
    unsigned u = __builtin_bit_cast(unsigned, f);
    u += 0x7fffu + ((u >> 16) & 1u);          // RNE
    return (ushort)(u >> 16);
}
static __device__ __forceinline__ unsigned cvt_pk_bf16(float lo, float hi) {
    unsigned d;
    asm("v_cvt_pk_bf16_f32 %0, %1, %2" : "=v"(d) : "v"(lo), "v"(hi));
    return d;
}
static __device__ __forceinline__ float fmax3_(float a, float b, float c) {
    return fmaxf(fmaxf(a, b), c);
}
// bijective XCD swizzle: consecutive logical ids land on the same XCD (requires nwg%8==0)
static __device__ __forceinline__ int xcd_logical(int bid, int nwg) {
    return (bid & 7) * (nwg >> 3) + (bid >> 3);
}

#define GLDS16(gsrc, ldst)                                                              \
    __builtin_amdgcn_global_load_lds((const __attribute__((address_space(1))) void*)(gsrc), \
                                     (__attribute__((address_space(3))) void*)(ldst), 16, 0, 0)

// ---------------- prep: x cast (blocks 0..8191) + weight transposes (8192..9215) ----------------
__global__ __launch_bounds__(256) void prep(const float* __restrict__ x,
                                            ushort* __restrict__ xb,
                                            const float* __restrict__ wqkv,
                                            ushort* __restrict__ wqkvT,
                                            const float* __restrict__ wout,
                                            ushort* __restrict__ woutT) {
    if (blockIdx.x < 8192) {
        const int i = blockIdx.x * 256 + threadIdx.x;   // 2097152 float4's
        const float4 v = ((const float4*)x)[i];
        ushort4 o;
        o.x = bf_bits(v.x); o.y = bf_bits(v.y); o.z = bf_bits(v.z); o.w = bf_bits(v.w);
        ((ushort4*)xb)[i] = o;
        return;
    }
    __shared__ float t[32][33];
    const int tx = threadIdx.x & 31, ty = threadIdx.x >> 5;
    const float* in;
    ushort* out;
    int n0, k0, N;
    float scale;
    int scaleRows;
    const int bid = blockIdx.x - 8192;
    if (bid < 768) {
        in = wqkv; out = wqkvT; N = 1536;
        n0 = (bid % 48) * 32; k0 = (bid / 48) * 32;
        scale = QSCALE_; scaleRows = 512;
    } else {
        in = wout; out = woutT; N = 512;
        const int b2 = bid - 768;
        n0 = (b2 % 16) * 32; k0 = (b2 / 16) * 32;
        scale = 1.f; scaleRows = 0;
    }
    for (int i = ty; i < 32; i += 8)
        t[i][tx] = in[(size_t)(k0 + i) * N + n0 + tx];
    __syncthreads();
    for (int i = ty; i < 32; i += 8) {
        const float s = (n0 + i < scaleRows) ? scale : 1.f;
        out[(size_t)(n0 + i) * 512 + k0 + tx] = bf_bits(t[tx][i] * s);
    }
}

// ---------------- C = A[M,K] @ BT[N,K]^T (+bias), bf16 MFMA, double-buffered ----------------
// R12-proven schedule: stage(t+1) issued FIRST, then frag reads. Do not reorder.
// Cb path: cols >= 1024 (V region) divert to vT[bh=128][dv=64][n=1024] (when VT != null).
__global__ __launch_bounds__(256) void gemm_bf16(const ushort* __restrict__ A,
                                                 const ushort* __restrict__ BT,
                                                 const float* __restrict__ bias,
                                                 float* __restrict__ C,
                                                 ushort* __restrict__ Cb,
                                                 ushort* __restrict__ VT,
                                                 int M, int N, int K, int nx) {
    __shared__ __align__(16) char lds[32768];
    const int logical = xcd_logical(blockIdx.x, gridDim.x);
    const int bx = logical % nx;
    const int by = logical / nx;
    const int tid = threadIdx.x;
    const int lane = tid & 63;
    const int w = tid >> 6;
    const int wr = w >> 1, wc = w & 1;
    const int fr = lane & 15;
    const int fg = lane >> 4;
    const int rowBase = by * 128;
    const int colBase = bx * 128;

    auto stageG = [&](int k0, int buf) {
#pragma unroll
        for (int r = 0; r < 2; ++r) {
            const unsigned boff = r * 4096u + w * 1024u + lane * 16u;
            const unsigned row = boff >> 6;
            const unsigned ke = (boff & 63u) >> 1;
            GLDS16(A + (size_t)(rowBase + row) * K + k0 + ke,
                   lds + buf * 8192 + r * 4096 + w * 1024);
            GLDS16(BT + (size_t)(colBase + row) * K + k0 + ke,
                   lds + 16384 + buf * 8192 + r * 4096 + w * 1024);
        }
    };

    f32x4 acc[4][4] = {};

    stageG(0, 0);
    __syncthreads();
    int cur = 0;
    const int nsteps = K / 32;

    for (int s = 0; s < nsteps; ++s) {
        if (s + 1 < nsteps) stageG((s + 1) * 32, cur ^ 1);
        const char* ab = lds + cur * 8192;
        const char* bb = lds + 16384 + cur * 8192;

        bf16x8 a_frag[4], b_frag[4];
#pragma unroll
        for (int mi = 0; mi < 4; ++mi)
            a_frag[mi] = *(const bf16x8*)(ab + (wr * 64 + mi * 16 + fr) * 64 + fg * 16);
#pragma unroll
        for (int ni = 0; ni < 4; ++ni)
            b_frag[ni] = *(const bf16x8*)(bb + (wc * 64 + ni * 16 + fr) * 64 + fg * 16);
#pragma unroll
        for (int mi = 0; mi < 4; ++mi)
#pragma unroll
            for (int ni = 0; ni < 4; ++ni)
                acc[mi][ni] = __builtin_amdgcn_mfma_f32_16x16x32_bf16(a_frag[mi], b_frag[ni],
                                                                      acc[mi][ni], 0, 0, 0);
        __syncthreads();
        cur ^= 1;
    }

#pragma unroll
    for (int ni = 0; ni < 4; ++ni) {
        const int col = colBase + wc * 64 + ni * 16 + fr;
        const float bv = bias ? bias[col] : 0.f;
#pragma unroll
        for (int mi = 0; mi < 4; ++mi) {
            const int row0 = rowBase + wr * 64 + mi * 16 + fg * 4;
            if (Cb) {
                if (VT && col >= 1024) {
                    const int hd = col - 1024;
                    const size_t vb = ((size_t)((row0 >> 10) * 8 + (hd >> 6)) * 64 + (hd & 63)) * 1024
                                      + (row0 & 1023);
                    ushort4 pk4;
                    pk4.x = bf_bits(acc[mi][ni][0]);
                    pk4.y = bf_bits(acc[mi][ni][1]);
                    pk4.z = bf_bits(acc[mi][ni][2]);
                    pk4.w = bf_bits(acc[mi][ni][3]);
                    *(ushort4*)(VT + vb) = pk4;
                } else {
#pragma unroll
                    for (int q = 0; q < 4; ++q)
                        Cb[(size_t)(row0 + q) * N + col] = bf_bits(acc[mi][ni][q]);
                }
            } else {
#pragma unroll
                for (int q = 0; q < 4; ++q)
                    C[(size_t)(row0 + q) * N + col] = acc[mi][ni][q] + bv;
            }
        }
    }
}

// ---------------- MFMA flash attention, swapped QK^T, in-register softmax ----------------
// R12-proven schedule: stage(t+1) issued FIRST in tile(). Do not reorder.
// 1-D grid 2048, XCD-swizzled (qt fast within bh).
__global__ __launch_bounds__(256) void attn_mfma(const ushort* __restrict__ qkv,
                                                 const ushort* __restrict__ vT,
                                                 ushort* __restrict__ aoutb) {
    __shared__ __align__(16) char lds[40960];  // K:[2]x8KB @0 ; VT:[2]x8KB @16384 ; P: @32768 + w*2048
    const int logical = xcd_logical(blockIdx.x, gridDim.x);
    const int qt = logical & 15;
    const int bh = logical >> 4;
    const int b = bh >> 3, h = bh & 7;
    const int tid = threadIdx.x;
    const int lane = tid & 63;
    const int w = tid >> 6;
    const int fr = lane & 15;
    const int fg = lane >> 4;

    const size_t nbase = (size_t)b * 1024;
    const int qrow0 = qt * 64;

    bf16x8 qf[2];
    {
        const size_t qa = (nbase + qrow0 + w * 16 + fr) * 1536 + h * 64;
        qf[0] = *(const bf16x8*)(qkv + qa + fg * 8);
        qf[1] = *(const bf16x8*)(qkv + qa + 32 + fg * 8);
    }

    bf16x8 onesf;
#pragma unroll
    for (int e = 0; e < 8; ++e) onesf[e] = __builtin_bit_cast(__bf16, (ushort)0x3F80);

    const int srow = w * 16 + (lane >> 3);
    const int slot = lane & 7;
    auto stage = [&](int kt, int buf) {
        char* kd = lds + buf * 8192;
        char* vd = lds + 16384 + buf * 8192;
#pragma unroll
        for (int r = 0; r < 2; ++r) {
            const int row = srow + r * 8;
            const int sw = slot ^ (row & 7);
            GLDS16(qkv + (nbase + kt * 64 + row) * 1536 + 512 + h * 64 + sw * 8,
                   kd + (w * 2 + r) * 1024);
            GLDS16(vT + ((size_t)bh * 64 + row) * 1024 + kt * 64 + sw * 8,
                   vd + (w * 2 + r) * 1024);
        }
    };

    f32x4 o[4] = {};                      // o[dvb]: q = fg*4+r, dv = dvb*16+fr
    f32x4 lacc = {};                      // l[q = fg*4+r]
    float mrow = -INFINITY;               // running max for q = fr (log2 domain)

    stage(0, 0);
    __syncthreads();
    char* const pbase = lds + 32768 + w * 2048;   // per-wave P[16 q][64 k] bf16, swizzled

    auto tile = [&](int kt, int cur) {
        if (kt < 15) stage(kt + 1, cur ^ 1);
        const char* kb = lds + cur * 8192;
        const char* vb = lds + 16384 + cur * 8192;

        // ---- S^T = K Q^T : lane (fr,fg) holds S[k=jb*16+fg*4+r][q=fr] ----
        f32x4 S[4];
        __builtin_amdgcn_s_setprio(1);
#pragma unroll
        for (int jb = 0; jb < 4; ++jb) {
            f32x4 a = {};
#pragma unroll
            for (int s = 0; s < 2; ++s) {
                const int row = jb * 16 + fr;
                const int c = s * 64 + fg * 16;
                const bf16x8 kf = *(const bf16x8*)(kb + row * 128 + (c ^ ((row & 7) << 4)));
                a = __builtin_amdgcn_mfma_f32_16x16x32_bf16(kf, qf[s], a, 0, 0, 0);
            }
            S[jb] = a;
        }
        __builtin_amdgcn_s_setprio(0);

        // ---- row max: max3 tree + cross-fg combine ----
        float tmax = fmax3_(S[0][0], S[0][1], S[0][2]);
        tmax = fmax3_(tmax, S[0][3], S[1][0]);
        tmax = fmax3_(tmax, S[1][1], S[1][2]);
        tmax = fmax3_(tmax, S[1][3], S[2][0]);
        tmax = fmax3_(tmax, S[2][1], S[2][2]);
        tmax = fmax3_(tmax, S[2][3], S[3][0]);
        tmax = fmax3_(tmax, S[3][1], S[3][2]);
        tmax = fmaxf(tmax, S[3][3]);
        tmax = fmaxf(tmax, __shfl_xor(tmax, 16));
        tmax = fmaxf(tmax, __shfl_xor(tmax, 32));

        // ---- defer-max: rescale only when a row grew > THR ----
        if (!__all(tmax - mrow <= RESCALE_THR_)) {
            const float mnew = fmaxf(mrow, tmax);
            const float corr = __builtin_amdgcn_exp2f(mrow - mnew);
            mrow = mnew;
#pragma unroll
            for (int r = 0; r < 4; ++r) {
                const float cr = __shfl(corr, fg * 4 + r);
                lacc[r] *= cr;
#pragma unroll
                for (int dvb = 0; dvb < 4; ++dvb) o[dvb][r] *= cr;
            }
        }

        // ---- P = 2^(S - m), pack (arithmetic 64b build), stage to per-wave LDS ----
#pragma unroll
        for (int jb = 0; jb < 4; ++jb) {
            const unsigned lo = cvt_pk_bf16(__builtin_amdgcn_exp2f(S[jb][0] - mrow),
                                            __builtin_amdgcn_exp2f(S[jb][1] - mrow));
            const unsigned hi = cvt_pk_bf16(__builtin_amdgcn_exp2f(S[jb][2] - mrow),
                                            __builtin_amdgcn_exp2f(S[jb][3] - mrow));
            const unsigned long long pv =
                (unsigned long long)lo | ((unsigned long long)hi << 32);
            *(unsigned long long*)(pbase + fr * 128 +
                                   ((jb * 32 + fg * 8) ^ ((fr & 7) << 4))) = pv;
        }

        // ---- fence: keep P ds_writes ordered before pf ds_reads ----
        asm volatile("" ::: "memory");

        // ---- O += P V ; l += P 1 (row-sum via MFMA) ----
        __builtin_amdgcn_s_setprio(1);
#pragma unroll
        for (int s = 0; s < 2; ++s) {
            const int pc = s * 64 + fg * 16;
            const bf16x8 pf = *(const bf16x8*)(pbase + fr * 128 + (pc ^ ((fr & 7) << 4)));
            lacc = __builtin_amdgcn_mfma_f32_16x16x32_bf16(pf, onesf, lacc, 0, 0, 0);
#pragma unroll
            for (int dvb = 0; dvb < 4; ++dvb) {
                const int vrow = dvb * 16 + fr;
                const bf16x8 vf = *(const bf16x8*)(vb + vrow * 128 + (pc ^ ((vrow & 7) << 4)));
                o[dvb] = __builtin_amdgcn_mfma_f32_16x16x32_bf16(pf, vf, o[dvb], 0, 0, 0);
            }
        }
        __builtin_amdgcn_s_setprio(0);
        __syncthreads();
    };

    for (int kt = 0; kt < 16; kt += 2) {
        tile(kt, 0);
        tile(kt + 1, 1);
    }

    // ---- epilogue: l already indexed by this lane's o-rows (q = fg*4+r) ----
#pragma unroll
    for (int r = 0; r < 4; ++r) {
        const float linv = 1.f / lacc[r];
        const size_t n = nbase + qrow0 + w * 16 + fg * 4 + r;
#pragma unroll
        for (int dvb = 0; dvb < 4; ++dvb)
            aoutb[n * 512 + h * 64 + dvb * 16 + fr] = bf_bits(o[dvb][r] * linv);
    }
}

extern "C" void kernel_launch(void* const* d_in, const int* in_sizes, int n_in,
                              void* d_out, int out_size, void* d_ws, size_t ws_size,
                              hipStream_t stream) {
    const float* x     = (const float*)d_in[0];
    const float* w_qkv = (const float*)d_in[1];
    const float* w_out = (const float*)d_in[2];
    const float* b_out = (const float*)d_in[3];
    float* out = (float*)d_out;

    char* ws = (char*)d_ws;
    ushort* qkvb  = (ushort*)ws;                                  // 48 MiB [16384,1536] (V cols unused)
    ushort* vT    = (ushort*)(ws + 50331648);                     // 16 MiB [128,64,1024]
    ushort* xb    = (ushort*)(ws + 50331648 + 16777216);          // 16 MiB
    ushort* aoutb = xb;                                           // aliased (xb dead after GEMM1)
    ushort* wqkvT = (ushort*)(ws + 50331648 + 33554432);          // 1.5 MiB
    ushort* woutT = (ushort*)(ws + 50331648 + 33554432 + 1572864);// 0.5 MiB

    const dim3 blk(256);
    // x cast + both weight transposes, one dispatch
    prep<<<dim3(9216), blk, 0, stream>>>(x, xb, w_qkv, wqkvT, w_out, woutT);
    // qkv (bf16) = x @ w_qkv ; V columns divert to vT
    gemm_bf16<<<dim3(1536), blk, 0, stream>>>(xb, wqkvT, nullptr, nullptr, qkvb, vT,
                                              16384, 1536, 512, 12);
    // attention (64-row q-tiles), XCD-swizzled
    attn_mfma<<<dim3(2048), blk, 0, stream>>>(qkvb, vT, aoutb);
    // out = aout @ w_out + b_out (f32)
    gemm_bf16<<<dim3(512), blk, 0, stream>>>(aoutb, woutT, b_out, out, nullptr, nullptr,
                                             16384, 512, 512, 4);
}